// Round 7
// baseline (1279.328 us; speedup 1.0000x reference)
//
#include <hip/hip_runtime.h>
#include <hip/hip_bf16.h>
#include <cstdint>
#include <cstddef>

#define DIM 192
#define NSL 11
#define NB 64
#define NN 4096
#define HIDN 128
#define NCHP 16        // chunks per batch in k_iter (256 rows each)
#define LN_EPS 1e-5f
#define EPS_A 1e-8f
#define SCALE_Q 0.07216878364870323f  // 192^-0.5

// ---------------------------------------------------------------- utilities
__device__ __forceinline__ float wred(float v) {
#pragma unroll
  for (int m = 32; m; m >>= 1) v += __shfl_xor(v, m, 64);
  return v;
}

// block-wide (192-thread, 3-wave) dual reduction. bufa/bufb are 3-float LDS scratch.
__device__ __forceinline__ void bred2(float& a, float& b, float* bufa, float* bufb,
                                      int wave, int lane) {
  a = wred(a); b = wred(b);
  if (lane == 0) { bufa[wave] = a; bufb[wave] = b; }
  __syncthreads();
  a = bufa[0] + bufa[1] + bufa[2];
  b = bufb[0] + bufb[1] + bufb[2];
  __syncthreads();   // scratch reusable after this
}

// ---------------------------------------------------------------- k_prep: one (b,slot) per block
// slot init + LN -> q -> folded query  (latency-bound fix: grid 64 -> 704 blocks)
__global__ __launch_bounds__(192, 4) void k_prep(
    const float* __restrict__ lnw, const float* __restrict__ lnb,
    const float* __restrict__ Wq, const float* __restrict__ bq,
    const float* __restrict__ Wk, const float* __restrict__ bk,
    const float* __restrict__ xw, const float* __restrict__ xb,
    const float* __restrict__ noise, const float* __restrict__ mu0, const float* __restrict__ sig,
    float* __restrict__ slots_ws,
    float* __restrict__ qt, float* __restrict__ t0g, float* __restrict__ cpg) {
  const int b = blockIdx.x, k = blockIdx.y, tid = threadIdx.x;
  const int wave = tid >> 6, lane = tid & 63;
  const int j = tid;
  __shared__ __align__(16) float sn[DIM];
  __shared__ __align__(16) float qv[DIM];
  __shared__ float bufa[3], bufb[3];

  const size_t kidx = (size_t)(b * NSL + k);
  float v = mu0[j] + sig[j] * noise[kidx * DIM + j];
  slots_ws[kidx * DIM + j] = v;

  float s = v, ss = v * v;
  bred2(s, ss, bufa, bufb, wave, lane);
  float mu = s * (1.0f / DIM), var = ss * (1.0f / DIM) - mu * mu;
  float rstd = rsqrtf(var + LN_EPS);
  sn[j] = (v - mu) * rstd * lnw[j] + lnb[j];
  __syncthreads();

  // q[j] = bq[j] + sum_d sn[d] * Wq[d*DIM + j]
  float q = bq[j];
  for (int d = 0; d < DIM; d += 4) {
    float w0 = Wq[(d + 0) * DIM + j], w1 = Wq[(d + 1) * DIM + j];
    float w2 = Wq[(d + 2) * DIM + j], w3 = Wq[(d + 3) * DIM + j];
    float4 s4 = *(const float4*)&sn[d];
    q = fmaf(s4.w, w3, fmaf(s4.z, w2, fmaf(s4.y, w1, fmaf(s4.x, w0, q))));
  }
  qv[j] = q;
  __syncthreads();

  // qk[j] = Wk[j,:] . q
  float qk = 0.f;
  const float* wkr = Wk + (size_t)j * DIM;
  for (int d = 0; d < DIM; d += 4) {
    float4 w4 = *(const float4*)(wkr + d);
    float4 q4 = *(const float4*)&qv[d];
    qk = fmaf(w4.w, q4.w, fmaf(w4.z, q4.z, fmaf(w4.y, q4.y, fmaf(w4.x, q4.x, qk))));
  }
  float qtv = SCALE_Q * xw[j] * qk;
  qt[kidx * DIM + j] = qtv;
  float r1 = qtv;
  float r2 = SCALE_Q * (xb[j] * qk + q * bk[j]);
  bred2(r1, r2, bufa, bufb, wave, lane);
  if (tid == 0) { t0g[kidx] = r1; cpg[kidx] = r2; }
}

// ---------------------------------------------------------------- fused iteration kernel (unchanged from R6)
// grid (64, 16) x 256 threads. Block handles 256 rows = 4 tiles of 64.
__global__ __launch_bounds__(256, 2) void k_iter(
    const float* __restrict__ x, const float* __restrict__ qt,
    const float* __restrict__ t0g, const float* __restrict__ cpg,
    float* __restrict__ attn_out, float* __restrict__ P1p,
    float* __restrict__ S_p, float* __restrict__ m1_p) {
  __shared__ float xs_raw[64 * 196];          // 64 rows, stride 196 floats (49 f4), XOR-swizzled cols
  __shared__ float qs[NSL * DIM];
  __shared__ __align__(16) float a_lds[64][12];
  __shared__ float rs_lds[64];
  __shared__ float t0s[NSL], cps[NSL];
  __shared__ float redS[4][NSL], redM[4][NSL];
  float4* xs4 = (float4*)xs_raw;

  const int b = blockIdx.x, ch = blockIdx.y, tid = threadIdx.x;
  const int lane = tid & 63, wv = tid >> 6;
  const int widx = tid & 15, g = tid >> 4;

  for (int t = tid; t < NSL * DIM; t += 256) qs[t] = qt[(size_t)b * NSL * DIM + t];
  if (tid < NSL) { t0s[tid] = t0g[b * NSL + tid]; cps[tid] = cpg[b * NSL + tid]; }

  const float* xbase = x + ((size_t)b * NN + ch * 256) * DIM;
  float4 xv[12];
  {
    const float4* gp = (const float4*)xbase;
#pragma unroll
    for (int i = 0; i < 12; ++i) xv[i] = gp[i * 256 + tid];
  }

  float acc[3][NSL];
  float sS[NSL], sM[NSL];
#pragma unroll
  for (int k = 0; k < NSL; ++k) {
    acc[0][k] = 0.f; acc[1][k] = 0.f; acc[2][k] = 0.f;
    sS[k] = 0.f; sM[k] = 0.f;
  }

#pragma unroll 1
  for (int T = 0; T < 4; ++T) {
    __syncthreads();                       // xs free (phase C of prev tile done)
#pragma unroll
    for (int i = 0; i < 12; ++i) {
      int f = i * 256 + tid;
      int row = f / 48, c4 = f % 48;
      xs4[row * 49 + (c4 ^ (row & 7))] = xv[i];
    }
    if (T < 3) {
      const float4* gp = (const float4*)(xbase + (size_t)(T + 1) * 64 * DIM);
#pragma unroll
      for (int i = 0; i < 12; ++i) xv[i] = gp[i * 256 + tid];
    }
    __syncthreads();                       // xs ready

    // ---- dots + LN stats
    float dot[4][NSL], st_s[4], st_ss[4];
#pragma unroll
    for (int rr = 0; rr < 4; ++rr) {
      st_s[rr] = 0.f; st_ss[rr] = 0.f;
#pragma unroll
      for (int k = 0; k < NSL; ++k) dot[rr][k] = 0.f;
    }
#pragma unroll
    for (int w = 0; w < 3; ++w) {
      const int c4 = widx + 16 * w;
      float4 xr[4];
#pragma unroll
      for (int rr = 0; rr < 4; ++rr) {
        const int r = 4 * g + rr;
        xr[rr] = xs4[r * 49 + (c4 ^ (r & 7))];
        st_s[rr] += (xr[rr].x + xr[rr].y) + (xr[rr].z + xr[rr].w);
        st_ss[rr] = fmaf(xr[rr].x, xr[rr].x, fmaf(xr[rr].y, xr[rr].y,
                    fmaf(xr[rr].z, xr[rr].z, fmaf(xr[rr].w, xr[rr].w, st_ss[rr]))));
      }
#pragma unroll
      for (int k = 0; k < NSL; ++k) {
        float4 qv = *(const float4*)&qs[k * DIM + 4 * c4];
#pragma unroll
        for (int rr = 0; rr < 4; ++rr)
          dot[rr][k] = fmaf(xr[rr].w, qv.w, fmaf(xr[rr].z, qv.z,
                       fmaf(xr[rr].y, qv.y, fmaf(xr[rr].x, qv.x, dot[rr][k]))));
      }
    }
    // ---- reduce across the 16 widx lanes
#pragma unroll
    for (int m = 1; m <= 8; m <<= 1) {
#pragma unroll
      for (int rr = 0; rr < 4; ++rr) {
        st_s[rr] += __shfl_xor(st_s[rr], m, 64);
        st_ss[rr] += __shfl_xor(st_ss[rr], m, 64);
#pragma unroll
        for (int k = 0; k < NSL; ++k) dot[rr][k] += __shfl_xor(dot[rr][k], m, 64);
      }
    }
    // ---- softmax on widx==0 lanes (one per 4 rows)
    if (widx == 0) {
#pragma unroll
      for (int rr = 0; rr < 4; ++rr) {
        const int r = 4 * g + rr;
        float mu = st_s[rr] * (1.0f / DIM);
        float var = st_ss[rr] * (1.0f / DIM) - mu * mu;
        float rstd = rsqrtf(var + LN_EPS);
        float murstd = mu * rstd;
        float dv[NSL];
#pragma unroll
        for (int k = 0; k < NSL; ++k) dv[k] = fmaf(rstd, dot[rr][k], fmaf(-murstd, t0s[k], cps[k]));
        float mx = dv[0];
#pragma unroll
        for (int k = 1; k < NSL; ++k) mx = fmaxf(mx, dv[k]);
        float es[NSL], sum = 0.f;
#pragma unroll
        for (int k = 0; k < NSL; ++k) { es[k] = __expf(dv[k] - mx); sum += es[k]; }
        float inv = 1.0f / sum;
#pragma unroll
        for (int k = 0; k < NSL; ++k) {
          float a = fmaf(es[k], inv, EPS_A);
          a_lds[r][k] = a;
          sS[k] += a;
          sM[k] = fmaf(a, murstd, sM[k]);
        }
        rs_lds[r] = rstd;
      }
    }
    __syncthreads();                       // a_lds, rs_lds ready; xs stable

    // ---- attn write (coalesced 64-float runs)
    {
      int idx = tid;
#pragma unroll
      for (int rep = 0; rep < 3; ++rep) {
        if (idx < NSL * 64) {
          int k = idx >> 6, r = idx & 63;
          attn_out[((size_t)(b * NSL + k)) * NN + ch * 256 + T * 64 + r] = a_lds[r][k];
        }
        idx += 256;
      }
    }
    // ---- phase C: acc[j][k] += a[r][k] * rstd_r * x[r][col]
#pragma unroll 4
    for (int i = 0; i < 16; ++i) {
      const int r = 4 * i + wv;
      float rst = rs_lds[r];
      float4 a0 = *(const float4*)&a_lds[r][0];
      float4 a1 = *(const float4*)&a_lds[r][4];
      float4 a2 = *(const float4*)&a_lds[r][8];
#pragma unroll
      for (int j = 0; j < 3; ++j) {
        const int col = lane + 64 * j;
        const int c4 = col >> 2;
        float xval = xs_raw[r * 196 + (((c4 ^ (r & 7)) << 2) | (col & 3))];
        float t1 = rst * xval;
        acc[j][0]  = fmaf(a0.x, t1, acc[j][0]);
        acc[j][1]  = fmaf(a0.y, t1, acc[j][1]);
        acc[j][2]  = fmaf(a0.z, t1, acc[j][2]);
        acc[j][3]  = fmaf(a0.w, t1, acc[j][3]);
        acc[j][4]  = fmaf(a1.x, t1, acc[j][4]);
        acc[j][5]  = fmaf(a1.y, t1, acc[j][5]);
        acc[j][6]  = fmaf(a1.z, t1, acc[j][6]);
        acc[j][7]  = fmaf(a1.w, t1, acc[j][7]);
        acc[j][8]  = fmaf(a2.x, t1, acc[j][8]);
        acc[j][9]  = fmaf(a2.y, t1, acc[j][9]);
        acc[j][10] = fmaf(a2.z, t1, acc[j][10]);
      }
    }
  }

  // ---- reduce acc across waves (alias xs_raw) and write P1 partials
  __syncthreads();
  float* accbuf = xs_raw;                  // 256*33 = 8448 floats < 12544
#pragma unroll
  for (int j = 0; j < 3; ++j)
#pragma unroll
    for (int k = 0; k < NSL; ++k)
      accbuf[tid * 33 + j * 11 + k] = acc[j][k];
  __syncthreads();
  if (tid < DIM) {
    const int l = tid & 63, j = tid >> 6;
#pragma unroll
    for (int k = 0; k < NSL; ++k) {
      float v = accbuf[(l) * 33 + j * 11 + k] + accbuf[(64 + l) * 33 + j * 11 + k]
              + accbuf[(128 + l) * 33 + j * 11 + k] + accbuf[(192 + l) * 33 + j * 11 + k];
      P1p[(((size_t)b * NCHP + ch) * NSL + k) * DIM + tid] = v;
    }
  }
#pragma unroll
  for (int k = 0; k < NSL; ++k) { sS[k] = wred(sS[k]); sM[k] = wred(sM[k]); }
  if (lane == 0) {
#pragma unroll
    for (int k = 0; k < NSL; ++k) { redS[wv][k] = sS[k]; redM[wv][k] = sM[k]; }
  }
  __syncthreads();
  if (tid < NSL) {
    S_p[((size_t)b * NCHP + ch) * NSL + tid]  = redS[0][tid] + redS[1][tid] + redS[2][tid] + redS[3][tid];
    m1_p[((size_t)b * NCHP + ch) * NSL + tid] = redM[0][tid] + redM[1][tid] + redM[2][tid] + redM[3][tid];
  }
}

// ---------------------------------------------------------------- k_step: one (b,slot) per block
// updates + GRU + LN + MLP + residual + next-iter prep.
// R6: grid 64 -> 2.2% occupancy, 176 us latency-bound. Now grid (64,11) = 704 blocks.
__global__ __launch_bounds__(192, 4) void k_step(
    const float* __restrict__ P1p, const float* __restrict__ m1_p, const float* __restrict__ S_p,
    const float* __restrict__ xw, const float* __restrict__ xb,
    const float* __restrict__ Wv, const float* __restrict__ bv,
    const float* __restrict__ slots_in,
    const float* __restrict__ Wih, const float* __restrict__ Whh,
    const float* __restrict__ bih, const float* __restrict__ bhh,
    const float* __restrict__ mw, const float* __restrict__ mb,
    const float* __restrict__ W1, const float* __restrict__ b1,
    const float* __restrict__ W2, const float* __restrict__ b2,
    const float* __restrict__ sw, const float* __restrict__ sb,
    const float* __restrict__ Wq, const float* __restrict__ bq,
    const float* __restrict__ Wk, const float* __restrict__ bk,
    float* __restrict__ slots_ws, float* __restrict__ slots_out,
    float* __restrict__ qt, float* __restrict__ t0g, float* __restrict__ cpg) {
  const int b = blockIdx.x, kk = blockIdx.y, tid = threadIdx.x;
  const int wave = tid >> 6, lane = tid & 63;
  const int j = tid;
  __shared__ __align__(16) float u[DIM];    // updates -> m -> sn
  __shared__ __align__(16) float hpv[DIM];  // prev slot
  __shared__ __align__(16) float qvv[DIM];  // q vector
  __shared__ __align__(16) float hid[HIDN];
  __shared__ float bufa[3], bufb[3];

  const size_t kidx = (size_t)(b * NSL + kk);

  // ---- updates input: sum partials
  float p = 0.f, S = 0.f, M = 0.f;
#pragma unroll
  for (int ch = 0; ch < NCHP; ++ch) {
    p += P1p[(((size_t)b * NCHP + ch) * NSL + kk) * DIM + j];
    S += S_p[((size_t)b * NCHP + ch) * NSL + kk];
    M += m1_p[((size_t)b * NCHP + ch) * NSL + kk];
  }
  float inv = 1.0f / S;
  u[j] = xw[j] * (p - M) * inv + xb[j];
  float hpj = slots_in[kidx * DIM + j];
  hpv[j] = hpj;
  __syncthreads();

  // ---- updates = xa @ Wv + bv  (column j)
  float upd = bv[j];
  for (int d = 0; d < DIM; d += 4) {
    float w0 = Wv[(d + 0) * DIM + j], w1 = Wv[(d + 1) * DIM + j];
    float w2 = Wv[(d + 2) * DIM + j], w3 = Wv[(d + 3) * DIM + j];
    float4 x4 = *(const float4*)&u[d];
    upd = fmaf(x4.w, w3, fmaf(x4.z, w2, fmaf(x4.y, w1, fmaf(x4.x, w0, upd))));
  }
  __syncthreads();
  u[j] = upd;
  __syncthreads();

  // ---- GRU: 6 dot products for column j
  float xr = bih[j], xz = bih[DIM + j], xn = bih[2 * DIM + j];
  float hr = bhh[j], hz = bhh[DIM + j], hn = bhh[2 * DIM + j];
  const float* wr = Wih + (size_t)j * DIM;
  const float* wz = Wih + (size_t)(DIM + j) * DIM;
  const float* wn = Wih + (size_t)(2 * DIM + j) * DIM;
  const float* vr = Whh + (size_t)j * DIM;
  const float* vz = Whh + (size_t)(DIM + j) * DIM;
  const float* vn = Whh + (size_t)(2 * DIM + j) * DIM;
  for (int d = 0; d < DIM; d += 4) {
    float4 u4 = *(const float4*)&u[d];
    float4 p4 = *(const float4*)&hpv[d];
    float4 ar  = *(const float4*)(wr + d);
    float4 az  = *(const float4*)(wz + d);
    float4 an  = *(const float4*)(wn + d);
    float4 br4 = *(const float4*)(vr + d);
    float4 bz4 = *(const float4*)(vz + d);
    float4 bn4 = *(const float4*)(vn + d);
    xr = fmaf(u4.w, ar.w, fmaf(u4.z, ar.z, fmaf(u4.y, ar.y, fmaf(u4.x, ar.x, xr))));
    xz = fmaf(u4.w, az.w, fmaf(u4.z, az.z, fmaf(u4.y, az.y, fmaf(u4.x, az.x, xz))));
    xn = fmaf(u4.w, an.w, fmaf(u4.z, an.z, fmaf(u4.y, an.y, fmaf(u4.x, an.x, xn))));
    hr = fmaf(p4.w, br4.w, fmaf(p4.z, br4.z, fmaf(p4.y, br4.y, fmaf(p4.x, br4.x, hr))));
    hz = fmaf(p4.w, bz4.w, fmaf(p4.z, bz4.z, fmaf(p4.y, bz4.y, fmaf(p4.x, bz4.x, hz))));
    hn = fmaf(p4.w, bn4.w, fmaf(p4.z, bn4.z, fmaf(p4.y, bn4.y, fmaf(p4.x, bn4.x, hn))));
  }
  float r = 1.f / (1.f + __expf(-(xr + hr)));
  float z = 1.f / (1.f + __expf(-(xz + hz)));
  float n = tanhf(xn + r * hn);
  float hval = (1.f - z) * n + z * hpj;
  __syncthreads();                 // all GRU reads of u done

  // ---- LN(h) -> m into u
  {
    float s = hval, ss = hval * hval;
    bred2(s, ss, bufa, bufb, wave, lane);
    float mu = s * (1.0f / DIM), var = ss * (1.0f / DIM) - mu * mu;
    float rstd = rsqrtf(var + LN_EPS);
    u[j] = (hval - mu) * rstd * mw[j] + mb[j];
  }
  __syncthreads();

  // ---- MLP1 (128 outputs)
  if (tid < HIDN) {
    float acc = b1[tid];
    for (int d = 0; d < DIM; d += 4) {
      float4 m4 = *(const float4*)&u[d];
      acc = fmaf(m4.x, W1[(d + 0) * HIDN + tid],
            fmaf(m4.y, W1[(d + 1) * HIDN + tid],
            fmaf(m4.z, W1[(d + 2) * HIDN + tid],
            fmaf(m4.w, W1[(d + 3) * HIDN + tid], acc))));
    }
    hid[tid] = fmaxf(acc, 0.f);
  }
  __syncthreads();

  // ---- MLP2 + residual
  float o = b2[j];
  for (int c = 0; c < HIDN; c += 4) {
    float4 h4 = *(const float4*)&hid[c];
    o = fmaf(h4.x, W2[(c + 0) * DIM + j],
        fmaf(h4.y, W2[(c + 1) * DIM + j],
        fmaf(h4.z, W2[(c + 2) * DIM + j],
        fmaf(h4.w, W2[(c + 3) * DIM + j], o))));
  }
  float outv = hval + o;
  slots_ws[kidx * DIM + j] = outv;
  slots_out[kidx * DIM + j] = outv;

  // ---- next-iter prep: LN(new slot) -> q -> folded query
  {
    float s = outv, ss = outv * outv;
    bred2(s, ss, bufa, bufb, wave, lane);
    float mu = s * (1.0f / DIM), var = ss * (1.0f / DIM) - mu * mu;
    float rstd = rsqrtf(var + LN_EPS);
    u[j] = (outv - mu) * rstd * sw[j] + sb[j];
  }
  __syncthreads();

  float q = bq[j];
  for (int d = 0; d < DIM; d += 4) {
    float w0 = Wq[(d + 0) * DIM + j], w1 = Wq[(d + 1) * DIM + j];
    float w2 = Wq[(d + 2) * DIM + j], w3 = Wq[(d + 3) * DIM + j];
    float4 s4 = *(const float4*)&u[d];
    q = fmaf(s4.w, w3, fmaf(s4.z, w2, fmaf(s4.y, w1, fmaf(s4.x, w0, q))));
  }
  qvv[j] = q;
  __syncthreads();

  float qk = 0.f;
  const float* wkr = Wk + (size_t)j * DIM;
  for (int d = 0; d < DIM; d += 4) {
    float4 w4 = *(const float4*)(wkr + d);
    float4 q4 = *(const float4*)&qvv[d];
    qk = fmaf(w4.w, q4.w, fmaf(w4.z, q4.z, fmaf(w4.y, q4.y, fmaf(w4.x, q4.x, qk))));
  }
  float qtv = SCALE_Q * xw[j] * qk;
  qt[kidx * DIM + j] = qtv;
  float r1 = qtv;
  float r2 = SCALE_Q * (xb[j] * qk + q * bk[j]);
  bred2(r1, r2, bufa, bufb, wave, lane);
  if (tid == 0) { t0g[kidx] = r1; cpg[kidx] = r2; }
}

// ---------------------------------------------------------------- launch
extern "C" void kernel_launch(void* const* d_in, const int* in_sizes, int n_in,
                              void* d_out, int out_size, void* d_ws, size_t ws_size,
                              hipStream_t stream) {
  const float* inputs      = (const float*)d_in[0];
  const float* noise       = (const float*)d_in[1];
  const float* slots_mu    = (const float*)d_in[2];
  const float* slots_sigma = (const float*)d_in[3];
  const float* ln_in_w     = (const float*)d_in[4];
  const float* ln_in_b     = (const float*)d_in[5];
  const float* ln_slots_w  = (const float*)d_in[6];
  const float* ln_slots_b  = (const float*)d_in[7];
  const float* ln_mlp_w    = (const float*)d_in[8];
  const float* ln_mlp_b    = (const float*)d_in[9];
  const float* Wq  = (const float*)d_in[10];
  const float* bq  = (const float*)d_in[11];
  const float* Wk  = (const float*)d_in[12];
  const float* bk  = (const float*)d_in[13];
  const float* Wv  = (const float*)d_in[14];
  const float* bv  = (const float*)d_in[15];
  const float* Wih = (const float*)d_in[16];
  const float* Whh = (const float*)d_in[17];
  const float* bih = (const float*)d_in[18];
  const float* bhh = (const float*)d_in[19];
  const float* W1  = (const float*)d_in[20];
  const float* b1  = (const float*)d_in[21];
  const float* W2  = (const float*)d_in[22];
  const float* b2  = (const float*)d_in[23];

  float* out = (float*)d_out;
  float* slots_out = out;                      // [64,11,192] fp32
  float* attn_out  = out + NB * NSL * DIM;     // [64,11,4096] fp32

  // workspace (~9.9 MiB):
  char* w = (char*)d_ws;
  float* slots = (float*)w;                    //  540672 B
  float* qt    = (float*)(w + 540672);         //  540672 B
  float* t0g   = (float*)(w + 1081344);        //    2816 B
  float* cpg   = (float*)(w + 1084160);        //    2816 B
  float* P1p   = (float*)(w + 1086976);        // 8650752 B  [64][16][11][192]
  float* S_p   = (float*)(w + 9737728);        //   45056 B  [64][16][11]
  float* m1_p  = (float*)(w + 9782784);        //   45056 B

  k_prep<<<dim3(NB, NSL), 192, 0, stream>>>(ln_slots_w, ln_slots_b, Wq, bq, Wk, bk,
                                            ln_in_w, ln_in_b, noise, slots_mu, slots_sigma,
                                            slots, qt, t0g, cpg);
  for (int it = 0; it < 3; ++it) {
    k_iter<<<dim3(NB, NCHP), 256, 0, stream>>>(inputs, qt, t0g, cpg, attn_out, P1p, S_p, m1_p);
    k_step<<<dim3(NB, NSL), 192, 0, stream>>>(P1p, m1_p, S_p, ln_in_w, ln_in_b, Wv, bv, slots,
                                              Wih, Whh, bih, bhh, ln_mlp_w, ln_mlp_b,
                                              W1, b1, W2, b2, ln_slots_w, ln_slots_b,
                                              Wq, bq, Wk, bk, slots, slots_out, qt, t0g, cpg);
  }
}

// Round 8
// 1028.336 us; speedup vs baseline: 1.2441x; 1.2441x over previous
//
#include <hip/hip_runtime.h>
#include <hip/hip_bf16.h>
#include <cstdint>
#include <cstddef>

#define DIM 192
#define NSL 11
#define NB 64
#define NN 4096
#define HIDN 128
#define NCHP 16        // chunks per batch in k_iter (256 rows each)
#define LN_EPS 1e-5f
#define EPS_A 1e-8f
#define SCALE_Q 0.07216878364870323f  // 192^-0.5

// ---------------------------------------------------------------- utilities
__device__ __forceinline__ float wred(float v) {
#pragma unroll
  for (int m = 32; m; m >>= 1) v += __shfl_xor(v, m, 64);
  return v;
}

// ---------------------------------------------------------------- one-time weight transpose (64x64 LDS tiles)
// WihT/WhhT: [192][576]  (WT[d*576 + row] = W[row*192 + d]); WkT: [192][192]
__global__ __launch_bounds__(256) void k_tr(
    const float* __restrict__ Wih, const float* __restrict__ Whh, const float* __restrict__ Wk,
    float* __restrict__ WihT, float* __restrict__ WhhT, float* __restrict__ WkT) {
  __shared__ float t[64][65];
  int tile = blockIdx.x;
  const float* src; float* dst; int R, C;
  if (tile < 27)      { src = Wih; dst = WihT; R = 576; C = 192; }
  else if (tile < 54) { src = Whh; dst = WhhT; R = 576; C = 192; tile -= 27; }
  else                { src = Wk;  dst = WkT;  R = 192; C = 192; tile -= 54; }
  const int ntc = C >> 6;
  const int tr = tile / ntc, tc = tile % ntc;
  const int lane = threadIdx.x & 63, w = threadIdx.x >> 6;
#pragma unroll
  for (int i = 0; i < 16; ++i) {
    int row = w * 16 + i;
    t[row][lane] = src[(size_t)(tr * 64 + row) * C + tc * 64 + lane];
  }
  __syncthreads();
#pragma unroll
  for (int i = 0; i < 16; ++i) {
    int row = w * 16 + i;
    dst[(size_t)(tc * 64 + row) * R + tr * 64 + lane] = t[lane][row];
  }
}

// ---------------------------------------------------------------- k_prep: grid (64,2), 6 slots/block, all-coalesced
__global__ __launch_bounds__(192) void k_prep(
    const float* __restrict__ lnw, const float* __restrict__ lnb,
    const float* __restrict__ Wq, const float* __restrict__ bq,
    const float* __restrict__ WkT, const float* __restrict__ bk,
    const float* __restrict__ xw, const float* __restrict__ xb,
    const float* __restrict__ noise, const float* __restrict__ mu0, const float* __restrict__ sig,
    float* __restrict__ slots_ws,
    float* __restrict__ qt, float* __restrict__ t0g, float* __restrict__ cpg) {
  const int b = blockIdx.x, kg = blockIdx.y, tid = threadIdx.x;
  const int k0 = kg * 6, kcnt = kg ? 5 : 6;
  const int wave = tid >> 6, lane = tid & 63;
  const int j = tid;
  __shared__ __align__(16) float sn[6][DIM];
  __shared__ __align__(16) float qb[6][DIM];
  __shared__ float red[3][6][2];

#pragma unroll
  for (int kk = 0; kk < 6; ++kk) {
    if (kk < kcnt) {
      float v = mu0[j] + sig[j] * noise[(size_t)(b * NSL + k0 + kk) * DIM + j];
      sn[kk][j] = v;
      slots_ws[(size_t)(b * NSL + k0 + kk) * DIM + j] = v;
    } else sn[kk][j] = 0.f;
  }
  __syncthreads();

  // LN in place (row owned by one wave; shfl-only reduction)
  for (int kk = wave; kk < 6; kk += 3) {
    float a = sn[kk][lane], c = sn[kk][lane + 64], e = sn[kk][lane + 128];
    float s = wred(a + c + e), ss = wred(a * a + c * c + e * e);
    float mu = s * (1.0f / DIM), var = ss * (1.0f / DIM) - mu * mu;
    float rstd = rsqrtf(var + LN_EPS);
    sn[kk][lane]       = (a - mu) * rstd * lnw[lane]       + lnb[lane];
    sn[kk][lane + 64]  = (c - mu) * rstd * lnw[lane + 64]  + lnb[lane + 64];
    sn[kk][lane + 128] = (e - mu) * rstd * lnw[lane + 128] + lnb[lane + 128];
  }
  __syncthreads();

  // q = sn @ Wq + bq   (Wq[d*DIM+j]: coalesced)
  float acc[6];
  const float bj = bq[j];
#pragma unroll
  for (int kk = 0; kk < 6; ++kk) acc[kk] = bj;
  for (int d = 0; d < DIM; d += 4) {
    float w0 = Wq[(d + 0) * DIM + j], w1 = Wq[(d + 1) * DIM + j];
    float w2 = Wq[(d + 2) * DIM + j], w3 = Wq[(d + 3) * DIM + j];
#pragma unroll
    for (int kk = 0; kk < 6; ++kk) {
      float4 s4 = *(const float4*)&sn[kk][d];
      acc[kk] = fmaf(s4.w, w3, fmaf(s4.z, w2, fmaf(s4.y, w1, fmaf(s4.x, w0, acc[kk]))));
    }
  }
#pragma unroll
  for (int kk = 0; kk < 6; ++kk) qb[kk][j] = acc[kk];
  __syncthreads();

  // qk[j] = sum_d WkT[d*192+j] * q[d]   (coalesced)
  float qk[6];
#pragma unroll
  for (int kk = 0; kk < 6; ++kk) qk[kk] = 0.f;
  for (int d = 0; d < DIM; d += 4) {
    float w0 = WkT[(d + 0) * DIM + j], w1 = WkT[(d + 1) * DIM + j];
    float w2 = WkT[(d + 2) * DIM + j], w3 = WkT[(d + 3) * DIM + j];
#pragma unroll
    for (int kk = 0; kk < 6; ++kk) {
      float4 q4 = *(const float4*)&qb[kk][d];
      qk[kk] = fmaf(q4.w, w3, fmaf(q4.z, w2, fmaf(q4.y, w1, fmaf(q4.x, w0, qk[kk]))));
    }
  }
  const float wj = xw[j], bxj = xb[j], bkj = bk[j];
#pragma unroll
  for (int kk = 0; kk < 6; ++kk) {
    float qtv = SCALE_Q * wj * qk[kk];
    if (kk < kcnt) qt[(size_t)(b * NSL + k0 + kk) * DIM + j] = qtv;
    float r1 = wred(qtv);
    float r2 = wred(SCALE_Q * (bxj * qk[kk] + qb[kk][j] * bkj));
    if (lane == 0) { red[wave][kk][0] = r1; red[wave][kk][1] = r2; }
  }
  __syncthreads();
  if (tid < kcnt) {
    t0g[b * NSL + k0 + tid] = red[0][tid][0] + red[1][tid][0] + red[2][tid][0];
    cpg[b * NSL + k0 + tid] = red[0][tid][1] + red[1][tid][1] + red[2][tid][1];
  }
}

// ---------------------------------------------------------------- fused iteration kernel (unchanged from R7)
__global__ __launch_bounds__(256, 2) void k_iter(
    const float* __restrict__ x, const float* __restrict__ qt,
    const float* __restrict__ t0g, const float* __restrict__ cpg,
    float* __restrict__ attn_out, float* __restrict__ P1p,
    float* __restrict__ S_p, float* __restrict__ m1_p) {
  __shared__ float xs_raw[64 * 196];
  __shared__ float qs[NSL * DIM];
  __shared__ __align__(16) float a_lds[64][12];
  __shared__ float rs_lds[64];
  __shared__ float t0s[NSL], cps[NSL];
  __shared__ float redS[4][NSL], redM[4][NSL];
  float4* xs4 = (float4*)xs_raw;

  const int b = blockIdx.x, ch = blockIdx.y, tid = threadIdx.x;
  const int lane = tid & 63, wv = tid >> 6;
  const int widx = tid & 15, g = tid >> 4;

  for (int t = tid; t < NSL * DIM; t += 256) qs[t] = qt[(size_t)b * NSL * DIM + t];
  if (tid < NSL) { t0s[tid] = t0g[b * NSL + tid]; cps[tid] = cpg[b * NSL + tid]; }

  const float* xbase = x + ((size_t)b * NN + ch * 256) * DIM;
  float4 xv[12];
  {
    const float4* gp = (const float4*)xbase;
#pragma unroll
    for (int i = 0; i < 12; ++i) xv[i] = gp[i * 256 + tid];
  }

  float acc[3][NSL];
  float sS[NSL], sM[NSL];
#pragma unroll
  for (int k = 0; k < NSL; ++k) {
    acc[0][k] = 0.f; acc[1][k] = 0.f; acc[2][k] = 0.f;
    sS[k] = 0.f; sM[k] = 0.f;
  }

#pragma unroll 1
  for (int T = 0; T < 4; ++T) {
    __syncthreads();
#pragma unroll
    for (int i = 0; i < 12; ++i) {
      int f = i * 256 + tid;
      int row = f / 48, c4 = f % 48;
      xs4[row * 49 + (c4 ^ (row & 7))] = xv[i];
    }
    if (T < 3) {
      const float4* gp = (const float4*)(xbase + (size_t)(T + 1) * 64 * DIM);
#pragma unroll
      for (int i = 0; i < 12; ++i) xv[i] = gp[i * 256 + tid];
    }
    __syncthreads();

    float dot[4][NSL], st_s[4], st_ss[4];
#pragma unroll
    for (int rr = 0; rr < 4; ++rr) {
      st_s[rr] = 0.f; st_ss[rr] = 0.f;
#pragma unroll
      for (int k = 0; k < NSL; ++k) dot[rr][k] = 0.f;
    }
#pragma unroll
    for (int w = 0; w < 3; ++w) {
      const int c4 = widx + 16 * w;
      float4 xr[4];
#pragma unroll
      for (int rr = 0; rr < 4; ++rr) {
        const int r = 4 * g + rr;
        xr[rr] = xs4[r * 49 + (c4 ^ (r & 7))];
        st_s[rr] += (xr[rr].x + xr[rr].y) + (xr[rr].z + xr[rr].w);
        st_ss[rr] = fmaf(xr[rr].x, xr[rr].x, fmaf(xr[rr].y, xr[rr].y,
                    fmaf(xr[rr].z, xr[rr].z, fmaf(xr[rr].w, xr[rr].w, st_ss[rr]))));
      }
#pragma unroll
      for (int k = 0; k < NSL; ++k) {
        float4 qv = *(const float4*)&qs[k * DIM + 4 * c4];
#pragma unroll
        for (int rr = 0; rr < 4; ++rr)
          dot[rr][k] = fmaf(xr[rr].w, qv.w, fmaf(xr[rr].z, qv.z,
                       fmaf(xr[rr].y, qv.y, fmaf(xr[rr].x, qv.x, dot[rr][k]))));
      }
    }
#pragma unroll
    for (int m = 1; m <= 8; m <<= 1) {
#pragma unroll
      for (int rr = 0; rr < 4; ++rr) {
        st_s[rr] += __shfl_xor(st_s[rr], m, 64);
        st_ss[rr] += __shfl_xor(st_ss[rr], m, 64);
#pragma unroll
        for (int k = 0; k < NSL; ++k) dot[rr][k] += __shfl_xor(dot[rr][k], m, 64);
      }
    }
    if (widx == 0) {
#pragma unroll
      for (int rr = 0; rr < 4; ++rr) {
        const int r = 4 * g + rr;
        float mu = st_s[rr] * (1.0f / DIM);
        float var = st_ss[rr] * (1.0f / DIM) - mu * mu;
        float rstd = rsqrtf(var + LN_EPS);
        float murstd = mu * rstd;
        float dv[NSL];
#pragma unroll
        for (int k = 0; k < NSL; ++k) dv[k] = fmaf(rstd, dot[rr][k], fmaf(-murstd, t0s[k], cps[k]));
        float mx = dv[0];
#pragma unroll
        for (int k = 1; k < NSL; ++k) mx = fmaxf(mx, dv[k]);
        float es[NSL], sum = 0.f;
#pragma unroll
        for (int k = 0; k < NSL; ++k) { es[k] = __expf(dv[k] - mx); sum += es[k]; }
        float inv = 1.0f / sum;
#pragma unroll
        for (int k = 0; k < NSL; ++k) {
          float a = fmaf(es[k], inv, EPS_A);
          a_lds[r][k] = a;
          sS[k] += a;
          sM[k] = fmaf(a, murstd, sM[k]);
        }
        rs_lds[r] = rstd;
      }
    }
    __syncthreads();

    {
      int idx = tid;
#pragma unroll
      for (int rep = 0; rep < 3; ++rep) {
        if (idx < NSL * 64) {
          int k = idx >> 6, r = idx & 63;
          attn_out[((size_t)(b * NSL + k)) * NN + ch * 256 + T * 64 + r] = a_lds[r][k];
        }
        idx += 256;
      }
    }
#pragma unroll 4
    for (int i = 0; i < 16; ++i) {
      const int r = 4 * i + wv;
      float rst = rs_lds[r];
      float4 a0 = *(const float4*)&a_lds[r][0];
      float4 a1 = *(const float4*)&a_lds[r][4];
      float4 a2 = *(const float4*)&a_lds[r][8];
#pragma unroll
      for (int j = 0; j < 3; ++j) {
        const int col = lane + 64 * j;
        const int c4 = col >> 2;
        float xval = xs_raw[r * 196 + (((c4 ^ (r & 7)) << 2) | (col & 3))];
        float t1 = rst * xval;
        acc[j][0]  = fmaf(a0.x, t1, acc[j][0]);
        acc[j][1]  = fmaf(a0.y, t1, acc[j][1]);
        acc[j][2]  = fmaf(a0.z, t1, acc[j][2]);
        acc[j][3]  = fmaf(a0.w, t1, acc[j][3]);
        acc[j][4]  = fmaf(a1.x, t1, acc[j][4]);
        acc[j][5]  = fmaf(a1.y, t1, acc[j][5]);
        acc[j][6]  = fmaf(a1.z, t1, acc[j][6]);
        acc[j][7]  = fmaf(a1.w, t1, acc[j][7]);
        acc[j][8]  = fmaf(a2.x, t1, acc[j][8]);
        acc[j][9]  = fmaf(a2.y, t1, acc[j][9]);
        acc[j][10] = fmaf(a2.z, t1, acc[j][10]);
      }
    }
  }

  __syncthreads();
  float* accbuf = xs_raw;
#pragma unroll
  for (int j = 0; j < 3; ++j)
#pragma unroll
    for (int k = 0; k < NSL; ++k)
      accbuf[tid * 33 + j * 11 + k] = acc[j][k];
  __syncthreads();
  if (tid < DIM) {
    const int l = tid & 63, j = tid >> 6;
#pragma unroll
    for (int k = 0; k < NSL; ++k) {
      float v = accbuf[(l) * 33 + j * 11 + k] + accbuf[(64 + l) * 33 + j * 11 + k]
              + accbuf[(128 + l) * 33 + j * 11 + k] + accbuf[(192 + l) * 33 + j * 11 + k];
      P1p[(((size_t)b * NCHP + ch) * NSL + k) * DIM + tid] = v;
    }
  }
#pragma unroll
  for (int k = 0; k < NSL; ++k) { sS[k] = wred(sS[k]); sM[k] = wred(sM[k]); }
  if (lane == 0) {
#pragma unroll
    for (int k = 0; k < NSL; ++k) { redS[wv][k] = sS[k]; redM[wv][k] = sM[k]; }
  }
  __syncthreads();
  if (tid < NSL) {
    S_p[((size_t)b * NCHP + ch) * NSL + tid]  = redS[0][tid] + redS[1][tid] + redS[2][tid] + redS[3][tid];
    m1_p[((size_t)b * NCHP + ch) * NSL + tid] = redM[0][tid] + redM[1][tid] + redM[2][tid] + redM[3][tid];
  }
}

// ---------------------------------------------------------------- k_step: grid (64,2), 6 slots/block, coalesced weights
__global__ __launch_bounds__(192) void k_step(
    const float* __restrict__ P1p, const float* __restrict__ m1_p, const float* __restrict__ S_p,
    const float* __restrict__ xw, const float* __restrict__ xb,
    const float* __restrict__ Wv, const float* __restrict__ bv,
    const float* __restrict__ slots_in,
    const float* __restrict__ WihT, const float* __restrict__ WhhT,
    const float* __restrict__ bih, const float* __restrict__ bhh,
    const float* __restrict__ mw, const float* __restrict__ mb,
    const float* __restrict__ W1, const float* __restrict__ b1,
    const float* __restrict__ W2, const float* __restrict__ b2,
    const float* __restrict__ sw, const float* __restrict__ sb,
    const float* __restrict__ Wq, const float* __restrict__ bq,
    const float* __restrict__ WkT, const float* __restrict__ bk,
    float* __restrict__ slots_ws, float* __restrict__ slots_out,
    float* __restrict__ qt, float* __restrict__ t0g, float* __restrict__ cpg) {
  const int b = blockIdx.x, kg = blockIdx.y, tid = threadIdx.x;
  const int k0 = kg * 6, kcnt = kg ? 5 : 6;
  const int wave = tid >> 6, lane = tid & 63;
  const int j = tid;
  __shared__ __align__(16) float u[6][DIM];    // xa -> updates -> m -> sn
  __shared__ __align__(16) float hp[6][DIM];   // prev slot -> new slot
  __shared__ __align__(16) float h[6][DIM];    // GRU out -> qb
  __shared__ __align__(16) float hid[6][HIDN];
  __shared__ float red[3][6][2];

  // ---- partials -> normalized LN'd attention-weighted mean (xa)
  const float wj = xw[j], bj = xb[j];
#pragma unroll
  for (int kk = 0; kk < 6; ++kk) {
    if (kk < kcnt) {
      float p = 0.f, S = 0.f, M = 0.f;
#pragma unroll
      for (int ch = 0; ch < NCHP; ++ch) {
        p += P1p[(((size_t)b * NCHP + ch) * NSL + k0 + kk) * DIM + j];
        S += S_p[((size_t)b * NCHP + ch) * NSL + k0 + kk];
        M += m1_p[((size_t)b * NCHP + ch) * NSL + k0 + kk];
      }
      float inv = 1.0f / S;
      u[kk][j]  = wj * (p - M) * inv + bj;
      hp[kk][j] = slots_in[(size_t)(b * NSL + k0 + kk) * DIM + j];
    } else { u[kk][j] = 0.f; hp[kk][j] = 0.f; }
  }
  __syncthreads();

  // ---- updates = xa @ Wv + bv (coalesced)
  float upd[6];
  const float bvj = bv[j];
#pragma unroll
  for (int kk = 0; kk < 6; ++kk) upd[kk] = bvj;
  for (int d = 0; d < DIM; d += 4) {
    float w0 = Wv[(d + 0) * DIM + j], w1 = Wv[(d + 1) * DIM + j];
    float w2 = Wv[(d + 2) * DIM + j], w3 = Wv[(d + 3) * DIM + j];
#pragma unroll
    for (int kk = 0; kk < 6; ++kk) {
      float4 x4 = *(const float4*)&u[kk][d];
      upd[kk] = fmaf(x4.w, w3, fmaf(x4.z, w2, fmaf(x4.y, w1, fmaf(x4.x, w0, upd[kk]))));
    }
  }
  __syncthreads();
#pragma unroll
  for (int kk = 0; kk < 6; ++kk) u[kk][j] = upd[kk];
  __syncthreads();

  // ---- GRU via transposed weights (coalesced scalar loads over d)
  float xr[6], xz[6], xn[6], hr[6], hz[6], hn[6];
  {
    float br_ = bih[j], bz_ = bih[DIM + j], bn_ = bih[2 * DIM + j];
    float cr_ = bhh[j], cz_ = bhh[DIM + j], cn_ = bhh[2 * DIM + j];
#pragma unroll
    for (int kk = 0; kk < 6; ++kk) { xr[kk] = br_; xz[kk] = bz_; xn[kk] = bn_; hr[kk] = cr_; hz[kk] = cz_; hn[kk] = cn_; }
  }
  for (int d = 0; d < DIM; d += 2) {
#pragma unroll
    for (int dd = 0; dd < 2; ++dd) {
      const float* ihrow = WihT + (size_t)(d + dd) * 576;
      const float* hhrow = WhhT + (size_t)(d + dd) * 576;
      float ar = ihrow[j], az = ihrow[192 + j], an = ihrow[384 + j];
      float br = hhrow[j], bz = hhrow[192 + j], bn = hhrow[384 + j];
#pragma unroll
      for (int kk = 0; kk < 6; ++kk) {
        float uv = u[kk][d + dd];
        float pv = hp[kk][d + dd];
        xr[kk] = fmaf(uv, ar, xr[kk]);
        xz[kk] = fmaf(uv, az, xz[kk]);
        xn[kk] = fmaf(uv, an, xn[kk]);
        hr[kk] = fmaf(pv, br, hr[kk]);
        hz[kk] = fmaf(pv, bz, hz[kk]);
        hn[kk] = fmaf(pv, bn, hn[kk]);
      }
    }
  }
#pragma unroll
  for (int kk = 0; kk < 6; ++kk) {
    float r = 1.f / (1.f + __expf(-(xr[kk] + hr[kk])));
    float z = 1.f / (1.f + __expf(-(xz[kk] + hz[kk])));
    float n = tanhf(xn[kk] + r * hn[kk]);
    h[kk][j] = (1.f - z) * n + z * hp[kk][j];
  }
  __syncthreads();

  // ---- LN(h) -> m (into u)
  for (int kk = wave; kk < 6; kk += 3) {
    float a = h[kk][lane], c = h[kk][lane + 64], e = h[kk][lane + 128];
    float s = wred(a + c + e), ss = wred(a * a + c * c + e * e);
    float mu = s * (1.0f / DIM), var = ss * (1.0f / DIM) - mu * mu;
    float rstd = rsqrtf(var + LN_EPS);
    u[kk][lane]       = (a - mu) * rstd * mw[lane]       + mb[lane];
    u[kk][lane + 64]  = (c - mu) * rstd * mw[lane + 64]  + mb[lane + 64];
    u[kk][lane + 128] = (e - mu) * rstd * mw[lane + 128] + mb[lane + 128];
  }
  __syncthreads();

  // ---- MLP1
  for (int t = tid; t < kcnt * HIDN; t += 192) {
    int kk = t >> 7, c = t & (HIDN - 1);
    float acc = b1[c];
    for (int d = 0; d < DIM; d += 4) {
      float4 m4 = *(const float4*)&u[kk][d];
      acc = fmaf(m4.x, W1[(d + 0) * HIDN + c],
            fmaf(m4.y, W1[(d + 1) * HIDN + c],
            fmaf(m4.z, W1[(d + 2) * HIDN + c],
            fmaf(m4.w, W1[(d + 3) * HIDN + c], acc))));
    }
    hid[kk][c] = fmaxf(acc, 0.f);
  }
  __syncthreads();

  // ---- MLP2 + residual; new slot into hp
#pragma unroll 1
  for (int kk = 0; kk < kcnt; ++kk) {
    float acc = b2[j];
    for (int c = 0; c < HIDN; c += 4) {
      float4 h4 = *(const float4*)&hid[kk][c];
      acc = fmaf(h4.x, W2[(c + 0) * DIM + j],
            fmaf(h4.y, W2[(c + 1) * DIM + j],
            fmaf(h4.z, W2[(c + 2) * DIM + j],
            fmaf(h4.w, W2[(c + 3) * DIM + j], acc))));
    }
    float outv = h[kk][j] + acc;
    size_t gi = (size_t)(b * NSL + k0 + kk) * DIM + j;
    slots_ws[gi] = outv;
    slots_out[gi] = outv;
    hp[kk][j] = outv;
  }
  __syncthreads();

  // ---- next-iter prep: LN(new slot) -> q -> folded query
  for (int kk = wave; kk < 6; kk += 3) {
    float a = hp[kk][lane], c = hp[kk][lane + 64], e = hp[kk][lane + 128];
    float s = wred(a + c + e), ss = wred(a * a + c * c + e * e);
    float mu = s * (1.0f / DIM), var = ss * (1.0f / DIM) - mu * mu;
    float rstd = rsqrtf(var + LN_EPS);
    u[kk][lane]       = (a - mu) * rstd * sw[lane]       + sb[lane];
    u[kk][lane + 64]  = (c - mu) * rstd * sw[lane + 64]  + sb[lane + 64];
    u[kk][lane + 128] = (e - mu) * rstd * sw[lane + 128] + sb[lane + 128];
  }
  __syncthreads();

  float qacc[6];
  const float bqj = bq[j];
#pragma unroll
  for (int kk = 0; kk < 6; ++kk) qacc[kk] = bqj;
  for (int d = 0; d < DIM; d += 4) {
    float w0 = Wq[(d + 0) * DIM + j], w1 = Wq[(d + 1) * DIM + j];
    float w2 = Wq[(d + 2) * DIM + j], w3 = Wq[(d + 3) * DIM + j];
#pragma unroll
    for (int kk = 0; kk < 6; ++kk) {
      float4 s4 = *(const float4*)&u[kk][d];
      qacc[kk] = fmaf(s4.w, w3, fmaf(s4.z, w2, fmaf(s4.y, w1, fmaf(s4.x, w0, qacc[kk]))));
    }
  }
  __syncthreads();
#pragma unroll
  for (int kk = 0; kk < 6; ++kk) h[kk][j] = qacc[kk];
  __syncthreads();

  float qk[6];
#pragma unroll
  for (int kk = 0; kk < 6; ++kk) qk[kk] = 0.f;
  for (int d = 0; d < DIM; d += 4) {
    float w0 = WkT[(d + 0) * DIM + j], w1 = WkT[(d + 1) * DIM + j];
    float w2 = WkT[(d + 2) * DIM + j], w3 = WkT[(d + 3) * DIM + j];
#pragma unroll
    for (int kk = 0; kk < 6; ++kk) {
      float4 q4 = *(const float4*)&h[kk][d];
      qk[kk] = fmaf(q4.w, w3, fmaf(q4.z, w2, fmaf(q4.y, w1, fmaf(q4.x, w0, qk[kk]))));
    }
  }
  const float wxj = xw[j], bxj = xb[j], bkj = bk[j];
#pragma unroll
  for (int kk = 0; kk < 6; ++kk) {
    float qtv = SCALE_Q * wxj * qk[kk];
    if (kk < kcnt) qt[(size_t)(b * NSL + k0 + kk) * DIM + j] = qtv;
    float r1 = wred(qtv);
    float r2 = wred(SCALE_Q * (bxj * qk[kk] + h[kk][j] * bkj));
    if (lane == 0) { red[wave][kk][0] = r1; red[wave][kk][1] = r2; }
  }
  __syncthreads();
  if (tid < kcnt) {
    t0g[b * NSL + k0 + tid] = red[0][tid][0] + red[1][tid][0] + red[2][tid][0];
    cpg[b * NSL + k0 + tid] = red[0][tid][1] + red[1][tid][1] + red[2][tid][1];
  }
}

// ---------------------------------------------------------------- launch
extern "C" void kernel_launch(void* const* d_in, const int* in_sizes, int n_in,
                              void* d_out, int out_size, void* d_ws, size_t ws_size,
                              hipStream_t stream) {
  const float* inputs      = (const float*)d_in[0];
  const float* noise       = (const float*)d_in[1];
  const float* slots_mu    = (const float*)d_in[2];
  const float* slots_sigma = (const float*)d_in[3];
  const float* ln_in_w     = (const float*)d_in[4];
  const float* ln_in_b     = (const float*)d_in[5];
  const float* ln_slots_w  = (const float*)d_in[6];
  const float* ln_slots_b  = (const float*)d_in[7];
  const float* ln_mlp_w    = (const float*)d_in[8];
  const float* ln_mlp_b    = (const float*)d_in[9];
  const float* Wq  = (const float*)d_in[10];
  const float* bq  = (const float*)d_in[11];
  const float* Wk  = (const float*)d_in[12];
  const float* bk  = (const float*)d_in[13];
  const float* Wv  = (const float*)d_in[14];
  const float* bv  = (const float*)d_in[15];
  const float* Wih = (const float*)d_in[16];
  const float* Whh = (const float*)d_in[17];
  const float* bih = (const float*)d_in[18];
  const float* bhh = (const float*)d_in[19];
  const float* W1  = (const float*)d_in[20];
  const float* b1  = (const float*)d_in[21];
  const float* W2  = (const float*)d_in[22];
  const float* b2  = (const float*)d_in[23];

  float* out = (float*)d_out;
  float* slots_out = out;                      // [64,11,192] fp32
  float* attn_out  = out + NB * NSL * DIM;     // [64,11,4096] fp32

  // workspace (~10.4 MiB):
  char* w = (char*)d_ws;
  float* slots = (float*)w;                    //  540672 B
  float* qt    = (float*)(w + 540672);         //  540672 B
  float* t0g   = (float*)(w + 1081344);        //    2816 B
  float* cpg   = (float*)(w + 1084160);        //    2816 B
  float* P1p   = (float*)(w + 1086976);        // 8650752 B  [64][16][11][192]
  float* S_p   = (float*)(w + 9737728);        //   45056 B  [64][16][11]
  float* m1_p  = (float*)(w + 9782784);        //   45056 B
  float* WihT  = (float*)(w + 9827840);        //  442368 B  [192][576]
  float* WhhT  = (float*)(w + 10270208);       //  442368 B  [192][576]
  float* WkT   = (float*)(w + 10712576);       //  147456 B  [192][192]

  k_tr<<<63, 256, 0, stream>>>(Wih, Whh, Wk, WihT, WhhT, WkT);
  k_prep<<<dim3(NB, 2), 192, 0, stream>>>(ln_slots_w, ln_slots_b, Wq, bq, WkT, bk,
                                          ln_in_w, ln_in_b, noise, slots_mu, slots_sigma,
                                          slots, qt, t0g, cpg);
  for (int it = 0; it < 3; ++it) {
    k_iter<<<dim3(NB, NCHP), 256, 0, stream>>>(inputs, qt, t0g, cpg, attn_out, P1p, S_p, m1_p);
    k_step<<<dim3(NB, 2), 192, 0, stream>>>(P1p, m1_p, S_p, ln_in_w, ln_in_b, Wv, bv, slots,
                                            WihT, WhhT, bih, bhh, ln_mlp_w, ln_mlp_b,
                                            W1, b1, W2, b2, ln_slots_w, ln_slots_b,
                                            Wq, bq, WkT, bk, slots, slots_out, qt, t0g, cpg);
  }
}

// Round 9
// 905.524 us; speedup vs baseline: 1.4128x; 1.1356x over previous
//
#include <hip/hip_runtime.h>
#include <hip/hip_bf16.h>
#include <cstdint>
#include <cstddef>

#define DIM 192
#define NSL 11
#define NB 64
#define NN 4096
#define HIDN 128
#define NCHP 16        // chunks per batch in k_iter (256 rows each)
#define LN_EPS 1e-5f
#define EPS_A 1e-8f
#define SCALE_Q 0.07216878364870323f  // 192^-0.5

// ---------------------------------------------------------------- utilities
__device__ __forceinline__ float wred(float v) {
#pragma unroll
  for (int m = 32; m; m >>= 1) v += __shfl_xor(v, m, 64);
  return v;
}

// ---------------------------------------------------------------- one-time weight transpose (64x64 LDS tiles)
__global__ __launch_bounds__(256) void k_tr(
    const float* __restrict__ Wih, const float* __restrict__ Whh, const float* __restrict__ Wk,
    float* __restrict__ WihT, float* __restrict__ WhhT, float* __restrict__ WkT) {
  __shared__ float t[64][65];
  int tile = blockIdx.x;
  const float* src; float* dst; int R, C;
  if (tile < 27)      { src = Wih; dst = WihT; R = 576; C = 192; }
  else if (tile < 54) { src = Whh; dst = WhhT; R = 576; C = 192; tile -= 27; }
  else                { src = Wk;  dst = WkT;  R = 192; C = 192; tile -= 54; }
  const int ntc = C >> 6;
  const int tr = tile / ntc, tc = tile % ntc;
  const int lane = threadIdx.x & 63, w = threadIdx.x >> 6;
#pragma unroll
  for (int i = 0; i < 16; ++i) {
    int row = w * 16 + i;
    t[row][lane] = src[(size_t)(tr * 64 + row) * C + tc * 64 + lane];
  }
  __syncthreads();
#pragma unroll
  for (int i = 0; i < 16; ++i) {
    int row = w * 16 + i;
    dst[(size_t)(tc * 64 + row) * R + tr * 64 + lane] = t[lane][row];
  }
}

// ---------------------------------------------------------------- k_prep: grid (64,4), 3 slots/block
__global__ __launch_bounds__(192) void k_prep(
    const float* __restrict__ lnw, const float* __restrict__ lnb,
    const float* __restrict__ Wq, const float* __restrict__ bq,
    const float* __restrict__ WkT, const float* __restrict__ bk,
    const float* __restrict__ xw, const float* __restrict__ xb,
    const float* __restrict__ noise, const float* __restrict__ mu0, const float* __restrict__ sig,
    float* __restrict__ slots_ws,
    float* __restrict__ qt, float* __restrict__ t0g, float* __restrict__ cpg) {
  const int b = blockIdx.x, kg = blockIdx.y, tid = threadIdx.x;
  const int k0 = kg * 3, kcnt = (kg == 3) ? 2 : 3;
  const int wave = tid >> 6, lane = tid & 63;
  const int j = tid;
  __shared__ __align__(16) float sn[3][DIM];
  __shared__ __align__(16) float qb[3][DIM];
  __shared__ float red[3][3][2];

#pragma unroll
  for (int kk = 0; kk < 3; ++kk) {
    if (kk < kcnt) {
      float v = mu0[j] + sig[j] * noise[(size_t)(b * NSL + k0 + kk) * DIM + j];
      sn[kk][j] = v;
      slots_ws[(size_t)(b * NSL + k0 + kk) * DIM + j] = v;
    } else sn[kk][j] = 0.f;
  }
  __syncthreads();

  for (int kk = wave; kk < 3; kk += 3) {
    float a = sn[kk][lane], c = sn[kk][lane + 64], e = sn[kk][lane + 128];
    float s = wred(a + c + e), ss = wred(a * a + c * c + e * e);
    float mu = s * (1.0f / DIM), var = ss * (1.0f / DIM) - mu * mu;
    float rstd = rsqrtf(var + LN_EPS);
    sn[kk][lane]       = (a - mu) * rstd * lnw[lane]       + lnb[lane];
    sn[kk][lane + 64]  = (c - mu) * rstd * lnw[lane + 64]  + lnb[lane + 64];
    sn[kk][lane + 128] = (e - mu) * rstd * lnw[lane + 128] + lnb[lane + 128];
  }
  __syncthreads();

  float acc[3];
  const float bj = bq[j];
#pragma unroll
  for (int kk = 0; kk < 3; ++kk) acc[kk] = bj;
  for (int d = 0; d < DIM; d += 4) {
    float w0 = Wq[(d + 0) * DIM + j], w1 = Wq[(d + 1) * DIM + j];
    float w2 = Wq[(d + 2) * DIM + j], w3 = Wq[(d + 3) * DIM + j];
#pragma unroll
    for (int kk = 0; kk < 3; ++kk) {
      float4 s4 = *(const float4*)&sn[kk][d];
      acc[kk] = fmaf(s4.w, w3, fmaf(s4.z, w2, fmaf(s4.y, w1, fmaf(s4.x, w0, acc[kk]))));
    }
  }
#pragma unroll
  for (int kk = 0; kk < 3; ++kk) qb[kk][j] = acc[kk];
  __syncthreads();

  float qk[3];
#pragma unroll
  for (int kk = 0; kk < 3; ++kk) qk[kk] = 0.f;
  for (int d = 0; d < DIM; d += 4) {
    float w0 = WkT[(d + 0) * DIM + j], w1 = WkT[(d + 1) * DIM + j];
    float w2 = WkT[(d + 2) * DIM + j], w3 = WkT[(d + 3) * DIM + j];
#pragma unroll
    for (int kk = 0; kk < 3; ++kk) {
      float4 q4 = *(const float4*)&qb[kk][d];
      qk[kk] = fmaf(q4.w, w3, fmaf(q4.z, w2, fmaf(q4.y, w1, fmaf(q4.x, w0, qk[kk]))));
    }
  }
  const float wj = xw[j], bxj = xb[j], bkj = bk[j];
#pragma unroll
  for (int kk = 0; kk < 3; ++kk) {
    float qtv = SCALE_Q * wj * qk[kk];
    if (kk < kcnt) qt[(size_t)(b * NSL + k0 + kk) * DIM + j] = qtv;
    float r1 = wred(qtv);
    float r2 = wred(SCALE_Q * (bxj * qk[kk] + qb[kk][j] * bkj));
    if (lane == 0) { red[wave][kk][0] = r1; red[wave][kk][1] = r2; }
  }
  __syncthreads();
  if (tid < kcnt) {
    t0g[b * NSL + k0 + tid] = red[0][tid][0] + red[1][tid][0] + red[2][tid][0];
    cpg[b * NSL + k0 + tid] = red[0][tid][1] + red[1][tid][1] + red[2][tid][1];
  }
}

// ---------------------------------------------------------------- fused iteration kernel
// LDS 62.5 KB already caps at 2 blocks/CU = 2 waves/EU; pin the register
// allocator to that occupancy so it may use 256 VGPRs (R8: launch_bounds(256,2)
// left VGPR=128 + 193 MB spill traffic; waves_per_eu(2,2) is the documented clamp).
__global__ __launch_bounds__(256) __attribute__((amdgpu_waves_per_eu(2, 2))) void k_iter(
    const float* __restrict__ x, const float* __restrict__ qt,
    const float* __restrict__ t0g, const float* __restrict__ cpg,
    float* __restrict__ attn_out, float* __restrict__ P1p,
    float* __restrict__ S_p, float* __restrict__ m1_p) {
  __shared__ float xs_raw[64 * 196];
  __shared__ float qs[NSL * DIM];
  __shared__ __align__(16) float a_lds[64][12];
  __shared__ float rs_lds[64];
  __shared__ float t0s[NSL], cps[NSL];
  __shared__ float redS[4][NSL], redM[4][NSL];
  float4* xs4 = (float4*)xs_raw;

  const int b = blockIdx.x, ch = blockIdx.y, tid = threadIdx.x;
  const int lane = tid & 63, wv = tid >> 6;
  const int widx = tid & 15, g = tid >> 4;

  for (int t = tid; t < NSL * DIM; t += 256) qs[t] = qt[(size_t)b * NSL * DIM + t];
  if (tid < NSL) { t0s[tid] = t0g[b * NSL + tid]; cps[tid] = cpg[b * NSL + tid]; }

  const float* xbase = x + ((size_t)b * NN + ch * 256) * DIM;
  float4 xv[12];
  {
    const float4* gp = (const float4*)xbase;
#pragma unroll
    for (int i = 0; i < 12; ++i) xv[i] = gp[i * 256 + tid];
  }

  float acc[3][NSL];
  float sS[NSL], sM[NSL];
#pragma unroll
  for (int k = 0; k < NSL; ++k) {
    acc[0][k] = 0.f; acc[1][k] = 0.f; acc[2][k] = 0.f;
    sS[k] = 0.f; sM[k] = 0.f;
  }

#pragma unroll 1
  for (int T = 0; T < 4; ++T) {
    __syncthreads();
#pragma unroll
    for (int i = 0; i < 12; ++i) {
      int f = i * 256 + tid;
      int row = f / 48, c4 = f % 48;
      xs4[row * 49 + (c4 ^ (row & 7))] = xv[i];
    }
    if (T < 3) {
      const float4* gp = (const float4*)(xbase + (size_t)(T + 1) * 64 * DIM);
#pragma unroll
      for (int i = 0; i < 12; ++i) xv[i] = gp[i * 256 + tid];
    }
    __syncthreads();

    float dot[4][NSL], st_s[4], st_ss[4];
#pragma unroll
    for (int rr = 0; rr < 4; ++rr) {
      st_s[rr] = 0.f; st_ss[rr] = 0.f;
#pragma unroll
      for (int k = 0; k < NSL; ++k) dot[rr][k] = 0.f;
    }
#pragma unroll
    for (int w = 0; w < 3; ++w) {
      const int c4 = widx + 16 * w;
      float4 xr[4];
#pragma unroll
      for (int rr = 0; rr < 4; ++rr) {
        const int r = 4 * g + rr;
        xr[rr] = xs4[r * 49 + (c4 ^ (r & 7))];
        st_s[rr] += (xr[rr].x + xr[rr].y) + (xr[rr].z + xr[rr].w);
        st_ss[rr] = fmaf(xr[rr].x, xr[rr].x, fmaf(xr[rr].y, xr[rr].y,
                    fmaf(xr[rr].z, xr[rr].z, fmaf(xr[rr].w, xr[rr].w, st_ss[rr]))));
      }
#pragma unroll
      for (int k = 0; k < NSL; ++k) {
        float4 qv = *(const float4*)&qs[k * DIM + 4 * c4];
#pragma unroll
        for (int rr = 0; rr < 4; ++rr)
          dot[rr][k] = fmaf(xr[rr].w, qv.w, fmaf(xr[rr].z, qv.z,
                       fmaf(xr[rr].y, qv.y, fmaf(xr[rr].x, qv.x, dot[rr][k]))));
      }
    }
#pragma unroll
    for (int m = 1; m <= 8; m <<= 1) {
#pragma unroll
      for (int rr = 0; rr < 4; ++rr) {
        st_s[rr] += __shfl_xor(st_s[rr], m, 64);
        st_ss[rr] += __shfl_xor(st_ss[rr], m, 64);
#pragma unroll
        for (int k = 0; k < NSL; ++k) dot[rr][k] += __shfl_xor(dot[rr][k], m, 64);
      }
    }
    if (widx == 0) {
#pragma unroll
      for (int rr = 0; rr < 4; ++rr) {
        const int r = 4 * g + rr;
        float mu = st_s[rr] * (1.0f / DIM);
        float var = st_ss[rr] * (1.0f / DIM) - mu * mu;
        float rstd = rsqrtf(var + LN_EPS);
        float murstd = mu * rstd;
        float dv[NSL];
#pragma unroll
        for (int k = 0; k < NSL; ++k) dv[k] = fmaf(rstd, dot[rr][k], fmaf(-murstd, t0s[k], cps[k]));
        float mx = dv[0];
#pragma unroll
        for (int k = 1; k < NSL; ++k) mx = fmaxf(mx, dv[k]);
        float es[NSL], sum = 0.f;
#pragma unroll
        for (int k = 0; k < NSL; ++k) { es[k] = __expf(dv[k] - mx); sum += es[k]; }
        float inv = 1.0f / sum;
#pragma unroll
        for (int k = 0; k < NSL; ++k) {
          float a = fmaf(es[k], inv, EPS_A);
          a_lds[r][k] = a;
          sS[k] += a;
          sM[k] = fmaf(a, murstd, sM[k]);
        }
        rs_lds[r] = rstd;
      }
    }
    __syncthreads();

    {
      int idx = tid;
#pragma unroll
      for (int rep = 0; rep < 3; ++rep) {
        if (idx < NSL * 64) {
          int k = idx >> 6, r = idx & 63;
          attn_out[((size_t)(b * NSL + k)) * NN + ch * 256 + T * 64 + r] = a_lds[r][k];
        }
        idx += 256;
      }
    }
#pragma unroll 4
    for (int i = 0; i < 16; ++i) {
      const int r = 4 * i + wv;
      float rst = rs_lds[r];
      float4 a0 = *(const float4*)&a_lds[r][0];
      float4 a1 = *(const float4*)&a_lds[r][4];
      float4 a2 = *(const float4*)&a_lds[r][8];
#pragma unroll
      for (int j = 0; j < 3; ++j) {
        const int col = lane + 64 * j;
        const int c4 = col >> 2;
        float xval = xs_raw[r * 196 + (((c4 ^ (r & 7)) << 2) | (col & 3))];
        float t1 = rst * xval;
        acc[j][0]  = fmaf(a0.x, t1, acc[j][0]);
        acc[j][1]  = fmaf(a0.y, t1, acc[j][1]);
        acc[j][2]  = fmaf(a0.z, t1, acc[j][2]);
        acc[j][3]  = fmaf(a0.w, t1, acc[j][3]);
        acc[j][4]  = fmaf(a1.x, t1, acc[j][4]);
        acc[j][5]  = fmaf(a1.y, t1, acc[j][5]);
        acc[j][6]  = fmaf(a1.z, t1, acc[j][6]);
        acc[j][7]  = fmaf(a1.w, t1, acc[j][7]);
        acc[j][8]  = fmaf(a2.x, t1, acc[j][8]);
        acc[j][9]  = fmaf(a2.y, t1, acc[j][9]);
        acc[j][10] = fmaf(a2.z, t1, acc[j][10]);
      }
    }
  }

  __syncthreads();
  float* accbuf = xs_raw;
#pragma unroll
  for (int j = 0; j < 3; ++j)
#pragma unroll
    for (int k = 0; k < NSL; ++k)
      accbuf[tid * 33 + j * 11 + k] = acc[j][k];
  __syncthreads();
  if (tid < DIM) {
    const int l = tid & 63, j = tid >> 6;
#pragma unroll
    for (int k = 0; k < NSL; ++k) {
      float v = accbuf[(l) * 33 + j * 11 + k] + accbuf[(64 + l) * 33 + j * 11 + k]
              + accbuf[(128 + l) * 33 + j * 11 + k] + accbuf[(192 + l) * 33 + j * 11 + k];
      P1p[(((size_t)b * NCHP + ch) * NSL + k) * DIM + tid] = v;
    }
  }
#pragma unroll
  for (int k = 0; k < NSL; ++k) { sS[k] = wred(sS[k]); sM[k] = wred(sM[k]); }
  if (lane == 0) {
#pragma unroll
    for (int k = 0; k < NSL; ++k) { redS[wv][k] = sS[k]; redM[wv][k] = sM[k]; }
  }
  __syncthreads();
  if (tid < NSL) {
    S_p[((size_t)b * NCHP + ch) * NSL + tid]  = redS[0][tid] + redS[1][tid] + redS[2][tid] + redS[3][tid];
    m1_p[((size_t)b * NCHP + ch) * NSL + tid] = redM[0][tid] + redM[1][tid] + redM[2][tid] + redM[3][tid];
  }
}

// ---------------------------------------------------------------- k_step: grid (64,4), 3 slots/block, coalesced weights
__global__ __launch_bounds__(192) void k_step(
    const float* __restrict__ P1p, const float* __restrict__ m1_p, const float* __restrict__ S_p,
    const float* __restrict__ xw, const float* __restrict__ xb,
    const float* __restrict__ Wv, const float* __restrict__ bv,
    const float* __restrict__ slots_in,
    const float* __restrict__ WihT, const float* __restrict__ WhhT,
    const float* __restrict__ bih, const float* __restrict__ bhh,
    const float* __restrict__ mw, const float* __restrict__ mb,
    const float* __restrict__ W1, const float* __restrict__ b1,
    const float* __restrict__ W2, const float* __restrict__ b2,
    const float* __restrict__ sw, const float* __restrict__ sb,
    const float* __restrict__ Wq, const float* __restrict__ bq,
    const float* __restrict__ WkT, const float* __restrict__ bk,
    float* __restrict__ slots_ws, float* __restrict__ slots_out,
    float* __restrict__ qt, float* __restrict__ t0g, float* __restrict__ cpg) {
  const int b = blockIdx.x, kg = blockIdx.y, tid = threadIdx.x;
  const int k0 = kg * 3, kcnt = (kg == 3) ? 2 : 3;
  const int wave = tid >> 6, lane = tid & 63;
  const int j = tid;
  __shared__ __align__(16) float u[3][DIM];
  __shared__ __align__(16) float hp[3][DIM];
  __shared__ __align__(16) float h[3][DIM];
  __shared__ __align__(16) float hid[3][HIDN];
  __shared__ float red[3][3][2];

  const float wj = xw[j], bj = xb[j];
#pragma unroll
  for (int kk = 0; kk < 3; ++kk) {
    if (kk < kcnt) {
      float p = 0.f, S = 0.f, M = 0.f;
#pragma unroll
      for (int ch = 0; ch < NCHP; ++ch) {
        p += P1p[(((size_t)b * NCHP + ch) * NSL + k0 + kk) * DIM + j];
        S += S_p[((size_t)b * NCHP + ch) * NSL + k0 + kk];
        M += m1_p[((size_t)b * NCHP + ch) * NSL + k0 + kk];
      }
      float inv = 1.0f / S;
      u[kk][j]  = wj * (p - M) * inv + bj;
      hp[kk][j] = slots_in[(size_t)(b * NSL + k0 + kk) * DIM + j];
    } else { u[kk][j] = 0.f; hp[kk][j] = 0.f; }
  }
  __syncthreads();

  float upd[3];
  const float bvj = bv[j];
#pragma unroll
  for (int kk = 0; kk < 3; ++kk) upd[kk] = bvj;
  for (int d = 0; d < DIM; d += 4) {
    float w0 = Wv[(d + 0) * DIM + j], w1 = Wv[(d + 1) * DIM + j];
    float w2 = Wv[(d + 2) * DIM + j], w3 = Wv[(d + 3) * DIM + j];
#pragma unroll
    for (int kk = 0; kk < 3; ++kk) {
      float4 x4 = *(const float4*)&u[kk][d];
      upd[kk] = fmaf(x4.w, w3, fmaf(x4.z, w2, fmaf(x4.y, w1, fmaf(x4.x, w0, upd[kk]))));
    }
  }
  __syncthreads();
#pragma unroll
  for (int kk = 0; kk < 3; ++kk) u[kk][j] = upd[kk];
  __syncthreads();

  float xr[3], xz[3], xn[3], hr[3], hz[3], hn[3];
  {
    float br_ = bih[j], bz_ = bih[DIM + j], bn_ = bih[2 * DIM + j];
    float cr_ = bhh[j], cz_ = bhh[DIM + j], cn_ = bhh[2 * DIM + j];
#pragma unroll
    for (int kk = 0; kk < 3; ++kk) { xr[kk] = br_; xz[kk] = bz_; xn[kk] = bn_; hr[kk] = cr_; hz[kk] = cz_; hn[kk] = cn_; }
  }
  for (int d = 0; d < DIM; d += 2) {
#pragma unroll
    for (int dd = 0; dd < 2; ++dd) {
      const float* ihrow = WihT + (size_t)(d + dd) * 576;
      const float* hhrow = WhhT + (size_t)(d + dd) * 576;
      float ar = ihrow[j], az = ihrow[192 + j], an = ihrow[384 + j];
      float br = hhrow[j], bz = hhrow[192 + j], bn = hhrow[384 + j];
#pragma unroll
      for (int kk = 0; kk < 3; ++kk) {
        float uv = u[kk][d + dd];
        float pv = hp[kk][d + dd];
        xr[kk] = fmaf(uv, ar, xr[kk]);
        xz[kk] = fmaf(uv, az, xz[kk]);
        xn[kk] = fmaf(uv, an, xn[kk]);
        hr[kk] = fmaf(pv, br, hr[kk]);
        hz[kk] = fmaf(pv, bz, hz[kk]);
        hn[kk] = fmaf(pv, bn, hn[kk]);
      }
    }
  }
#pragma unroll
  for (int kk = 0; kk < 3; ++kk) {
    float r = 1.f / (1.f + __expf(-(xr[kk] + hr[kk])));
    float z = 1.f / (1.f + __expf(-(xz[kk] + hz[kk])));
    float n = tanhf(xn[kk] + r * hn[kk]);
    h[kk][j] = (1.f - z) * n + z * hp[kk][j];
  }
  __syncthreads();

  for (int kk = wave; kk < 3; kk += 3) {
    float a = h[kk][lane], c = h[kk][lane + 64], e = h[kk][lane + 128];
    float s = wred(a + c + e), ss = wred(a * a + c * c + e * e);
    float mu = s * (1.0f / DIM), var = ss * (1.0f / DIM) - mu * mu;
    float rstd = rsqrtf(var + LN_EPS);
    u[kk][lane]       = (a - mu) * rstd * mw[lane]       + mb[lane];
    u[kk][lane + 64]  = (c - mu) * rstd * mw[lane + 64]  + mb[lane + 64];
    u[kk][lane + 128] = (e - mu) * rstd * mw[lane + 128] + mb[lane + 128];
  }
  __syncthreads();

  for (int t = tid; t < kcnt * HIDN; t += 192) {
    int kk = t >> 7, c = t & (HIDN - 1);
    float acc = b1[c];
    for (int d = 0; d < DIM; d += 4) {
      float4 m4 = *(const float4*)&u[kk][d];
      acc = fmaf(m4.x, W1[(d + 0) * HIDN + c],
            fmaf(m4.y, W1[(d + 1) * HIDN + c],
            fmaf(m4.z, W1[(d + 2) * HIDN + c],
            fmaf(m4.w, W1[(d + 3) * HIDN + c], acc))));
    }
    hid[kk][c] = fmaxf(acc, 0.f);
  }
  __syncthreads();

#pragma unroll 1
  for (int kk = 0; kk < kcnt; ++kk) {
    float acc = b2[j];
    for (int c = 0; c < HIDN; c += 4) {
      float4 h4 = *(const float4*)&hid[kk][c];
      acc = fmaf(h4.x, W2[(c + 0) * DIM + j],
            fmaf(h4.y, W2[(c + 1) * DIM + j],
            fmaf(h4.z, W2[(c + 2) * DIM + j],
            fmaf(h4.w, W2[(c + 3) * DIM + j], acc))));
    }
    float outv = h[kk][j] + acc;
    size_t gi = (size_t)(b * NSL + k0 + kk) * DIM + j;
    slots_ws[gi] = outv;
    slots_out[gi] = outv;
    hp[kk][j] = outv;
  }
  __syncthreads();

  for (int kk = wave; kk < 3; kk += 3) {
    float a = hp[kk][lane], c = hp[kk][lane + 64], e = hp[kk][lane + 128];
    float s = wred(a + c + e), ss = wred(a * a + c * c + e * e);
    float mu = s * (1.0f / DIM), var = ss * (1.0f / DIM) - mu * mu;
    float rstd = rsqrtf(var + LN_EPS);
    u[kk][lane]       = (a - mu) * rstd * sw[lane]       + sb[lane];
    u[kk][lane + 64]  = (c - mu) * rstd * sw[lane + 64]  + sb[lane + 64];
    u[kk][lane + 128] = (e - mu) * rstd * sw[lane + 128] + sb[lane + 128];
  }
  __syncthreads();

  float qacc[3];
  const float bqj = bq[j];
#pragma unroll
  for (int kk = 0; kk < 3; ++kk) qacc[kk] = bqj;
  for (int d = 0; d < DIM; d += 4) {
    float w0 = Wq[(d + 0) * DIM + j], w1 = Wq[(d + 1) * DIM + j];
    float w2 = Wq[(d + 2) * DIM + j], w3 = Wq[(d + 3) * DIM + j];
#pragma unroll
    for (int kk = 0; kk < 3; ++kk) {
      float4 s4 = *(const float4*)&u[kk][d];
      qacc[kk] = fmaf(s4.w, w3, fmaf(s4.z, w2, fmaf(s4.y, w1, fmaf(s4.x, w0, qacc[kk]))));
    }
  }
  __syncthreads();
#pragma unroll
  for (int kk = 0; kk < 3; ++kk) h[kk][j] = qacc[kk];
  __syncthreads();

  float qk[3];
#pragma unroll
  for (int kk = 0; kk < 3; ++kk) qk[kk] = 0.f;
  for (int d = 0; d < DIM; d += 4) {
    float w0 = WkT[(d + 0) * DIM + j], w1 = WkT[(d + 1) * DIM + j];
    float w2 = WkT[(d + 2) * DIM + j], w3 = WkT[(d + 3) * DIM + j];
#pragma unroll
    for (int kk = 0; kk < 3; ++kk) {
      float4 q4 = *(const float4*)&h[kk][d];
      qk[kk] = fmaf(q4.w, w3, fmaf(q4.z, w2, fmaf(q4.y, w1, fmaf(q4.x, w0, qk[kk]))));
    }
  }
  const float wxj = xw[j], bxj = xb[j], bkj = bk[j];
#pragma unroll
  for (int kk = 0; kk < 3; ++kk) {
    float qtv = SCALE_Q * wxj * qk[kk];
    if (kk < kcnt) qt[(size_t)(b * NSL + k0 + kk) * DIM + j] = qtv;
    float r1 = wred(qtv);
    float r2 = wred(SCALE_Q * (bxj * qk[kk] + h[kk][j] * bkj));
    if (lane == 0) { red[wave][kk][0] = r1; red[wave][kk][1] = r2; }
  }
  __syncthreads();
  if (tid < kcnt) {
    t0g[b * NSL + k0 + tid] = red[0][tid][0] + red[1][tid][0] + red[2][tid][0];
    cpg[b * NSL + k0 + tid] = red[0][tid][1] + red[1][tid][1] + red[2][tid][1];
  }
}

// ---------------------------------------------------------------- launch
extern "C" void kernel_launch(void* const* d_in, const int* in_sizes, int n_in,
                              void* d_out, int out_size, void* d_ws, size_t ws_size,
                              hipStream_t stream) {
  const float* inputs      = (const float*)d_in[0];
  const float* noise       = (const float*)d_in[1];
  const float* slots_mu    = (const float*)d_in[2];
  const float* slots_sigma = (const float*)d_in[3];
  const float* ln_in_w     = (const float*)d_in[4];
  const float* ln_in_b     = (const float*)d_in[5];
  const float* ln_slots_w  = (const float*)d_in[6];
  const float* ln_slots_b  = (const float*)d_in[7];
  const float* ln_mlp_w    = (const float*)d_in[8];
  const float* ln_mlp_b    = (const float*)d_in[9];
  const float* Wq  = (const float*)d_in[10];
  const float* bq  = (const float*)d_in[11];
  const float* Wk  = (const float*)d_in[12];
  const float* bk  = (const float*)d_in[13];
  const float* Wv  = (const float*)d_in[14];
  const float* bv  = (const float*)d_in[15];
  const float* Wih = (const float*)d_in[16];
  const float* Whh = (const float*)d_in[17];
  const float* bih = (const float*)d_in[18];
  const float* bhh = (const float*)d_in[19];
  const float* W1  = (const float*)d_in[20];
  const float* b1  = (const float*)d_in[21];
  const float* W2  = (const float*)d_in[22];
  const float* b2  = (const float*)d_in[23];

  float* out = (float*)d_out;
  float* slots_out = out;                      // [64,11,192] fp32
  float* attn_out  = out + NB * NSL * DIM;     // [64,11,4096] fp32

  char* w = (char*)d_ws;
  float* slots = (float*)w;                    //  540672 B
  float* qt    = (float*)(w + 540672);         //  540672 B
  float* t0g   = (float*)(w + 1081344);        //    2816 B
  float* cpg   = (float*)(w + 1084160);        //    2816 B
  float* P1p   = (float*)(w + 1086976);        // 8650752 B  [64][16][11][192]
  float* S_p   = (float*)(w + 9737728);        //   45056 B  [64][16][11]
  float* m1_p  = (float*)(w + 9782784);        //   45056 B
  float* WihT  = (float*)(w + 9827840);        //  442368 B  [192][576]
  float* WhhT  = (float*)(w + 10270208);       //  442368 B  [192][576]
  float* WkT   = (float*)(w + 10712576);       //  147456 B  [192][192]

  k_tr<<<63, 256, 0, stream>>>(Wih, Whh, Wk, WihT, WhhT, WkT);
  k_prep<<<dim3(NB, 4), 192, 0, stream>>>(ln_slots_w, ln_slots_b, Wq, bq, WkT, bk,
                                          ln_in_w, ln_in_b, noise, slots_mu, slots_sigma,
                                          slots, qt, t0g, cpg);
  for (int it = 0; it < 3; ++it) {
    k_iter<<<dim3(NB, NCHP), 256, 0, stream>>>(inputs, qt, t0g, cpg, attn_out, P1p, S_p, m1_p);
    k_step<<<dim3(NB, 4), 192, 0, stream>>>(P1p, m1_p, S_p, ln_in_w, ln_in_b, Wv, bv, slots,
                                            WihT, WhhT, bih, bhh, ln_mlp_w, ln_mlp_b,
                                            W1, b1, W2, b2, ln_slots_w, ln_slots_b,
                                            Wq, bq, WkT, bk, slots, slots_out, qt, t0g, cpg);
  }
}